// Round 24
// baseline (232.207 us; speedup 1.0000x reference)
//
#include <hip/hip_runtime.h>
#include <hip/hip_bf16.h>

#define MODS 3
#define BSZ 2
#define LSEQ 2048
#define DMODEL 512
#define DINNER 1024
#define DTRANK 32
#define NSTATE 16
#define DCONV 4
#define MROWS (BSZ*LSEQ)   // 4096
#define NCHUNK 128
#define CHUNK 16           // LSEQ / NCHUNK

#define LOG2E 1.44269504088896f
#define LN2   0.69314718055995f

typedef __attribute__((ext_vector_type(8))) short short8v;
typedef __attribute__((ext_vector_type(4))) short short4v;
typedef __attribute__((ext_vector_type(2))) short short2v;
typedef __attribute__((ext_vector_type(4))) float f32x4;

#if __has_builtin(__builtin_amdgcn_exp2f)
#define EXP2F __builtin_amdgcn_exp2f
#else
#define EXP2F exp2f
#endif
#if __has_builtin(__builtin_amdgcn_rcpf)
#define RCPF __builtin_amdgcn_rcpf
#else
#define RCPF(x) (1.0f / (x))
#endif

__device__ __forceinline__ short f2bf(float x) {
    __hip_bfloat16 h = __float2bfloat16(x);
    return __builtin_bit_cast(short, h);
}
__device__ __forceinline__ float bf2f(short s) {
    return __uint_as_float(((unsigned)(unsigned short)s) << 16);
}
__device__ __forceinline__ void gl_lds16(const short* g, short* l) {
    __builtin_amdgcn_global_load_lds(
        (const __attribute__((address_space(1))) unsigned int*)g,
        (__attribute__((address_space(3))) unsigned int*)l, 16, 0, 0);
}
__device__ __forceinline__ float sigmoid_f(float x) {
    return RCPF(1.f + EXP2F(-x * LOG2E));
}

// ============ pipelined 256x128 GEMM for in_proj (M=4096,N=2048,K=512) ============
#define MFMAQ(QR)                                                                  \
    _Pragma("unroll")                                                              \
    for (int rf = 0; rf < 2; ++rf)                                                 \
        _Pragma("unroll")                                                          \
        for (int cf = 0; cf < 2; ++cf)                                             \
            _Pragma("unroll")                                                      \
            for (int kh = 0; kh < 2; ++kh)                                         \
                acc[QR][rf][cf] = __builtin_amdgcn_mfma_f32_16x16x32_bf16(         \
                    afr[rf][kh], bfr[cf][kh], acc[QR][rf][cf], 0, 0, 0);

__global__ __launch_bounds__(1024) void gemm8p_inproj(
    const __hip_bfloat16* __restrict__ A_, const __hip_bfloat16* __restrict__ B_,
    __hip_bfloat16* __restrict__ C_)
{
    constexpr int NT = 8;                 // K=512 / BK=64
    __shared__ alignas(16) short As[2 * 16384];
    __shared__ alignas(16) short Bs[2 * 8192];
    const int z = blockIdx.z;
    const int bm0 = blockIdx.x * 256;
    const int bn0 = blockIdx.y * 128;
    const short* Ag = (const short*)A_ + (long)z * 2097152 + (long)bm0 * 512;
    const short* Bg = (const short*)B_ + (long)z * 1048576 + (long)bn0 * 512;
    short* Cg = (short*)C_ + (long)z * 8388608;
    const int tid = threadIdx.x;
    const int lane = tid & 63;
    const int w = tid >> 6;
    const int wr = w >> 2;
    const int wc = w & 3;
    const int lr = lane & 15;
    const int sidx = lane >> 4;
    const int srow_l = tid >> 3;
    const int sgoff = ((tid & 7) ^ (srow_l & 7)) * 8;

    f32x4 acc[2][2][2];
    #pragma unroll
    for (int a = 0; a < 2; ++a)
        #pragma unroll
        for (int b = 0; b < 2; ++b)
            #pragma unroll
            for (int c = 0; c < 2; ++c)
                acc[a][b][c] = (f32x4){0.f, 0.f, 0.f, 0.f};

    short8v afr[2][2];
    short8v bfr[2][2];

    auto stageA = [&](int buf, int half, int t) {
        const int row = half * 128 + srow_l;
        gl_lds16(Ag + (long)row * 512 + t * 64 + sgoff,
                 As + buf * 16384 + half * 8192 + tid * 8);
    };
    auto stageB = [&](int buf, int t) {
        const int row = srow_l;
        gl_lds16(Bg + (long)row * 512 + t * 64 + sgoff,
                 Bs + buf * 8192 + tid * 8);
    };
    auto loadA = [&](int buf, int qr) {
        #pragma unroll
        for (int rf = 0; rf < 2; ++rf)
            #pragma unroll
            for (int kh = 0; kh < 2; ++kh) {
                const int ra = qr * 128 + wr * 32 + rf * 16 + lr;
                const int g = kh * 4 + sidx;
                afr[rf][kh] = *(const short8v*)&As[buf * 16384 + ra * 64 + ((g ^ (ra & 7)) << 3)];
            }
    };
    auto loadB = [&](int buf) {
        #pragma unroll
        for (int cf = 0; cf < 2; ++cf)
            #pragma unroll
            for (int kh = 0; kh < 2; ++kh) {
                const int rb = wc * 32 + cf * 16 + lr;
                const int g = kh * 4 + sidx;
                bfr[cf][kh] = *(const short8v*)&Bs[buf * 8192 + rb * 64 + ((g ^ (rb & 7)) << 3)];
            }
    };

    stageA(0, 0, 0); stageB(0, 0); stageA(0, 1, 0);

    for (int t = 0; t < NT; ++t) {
        const int p = t & 1;
        const bool stg = (t + 1) < NT;
        if (stg) { stageA(p ^ 1, 0, t + 1); stageB(p ^ 1, t + 1);
                   asm volatile("s_waitcnt vmcnt(3)" ::: "memory"); }
        else       asm volatile("s_waitcnt vmcnt(1)" ::: "memory");
        asm volatile("s_barrier" ::: "memory");
        loadA(p, 0); loadB(p);
        MFMAQ(0)
        asm volatile("s_barrier" ::: "memory");
        if (stg) { stageA(p ^ 1, 1, t + 1);
                   asm volatile("s_waitcnt vmcnt(3)" ::: "memory"); }
        else       asm volatile("s_waitcnt vmcnt(0)" ::: "memory");
        asm volatile("s_barrier" ::: "memory");
        loadA(p, 1);
        MFMAQ(1)
        asm volatile("s_barrier" ::: "memory");
    }

    #pragma unroll
    for (int qr = 0; qr < 2; ++qr)
        #pragma unroll
        for (int rf = 0; rf < 2; ++rf)
            #pragma unroll
            for (int r = 0; r < 4; ++r) {
                const int row = bm0 + qr * 128 + wr * 32 + rf * 16 + (lane >> 4) * 4 + r;
                #pragma unroll
                for (int cf = 0; cf < 2; ++cf) {
                    const int col = bn0 + wc * 32 + cf * 16 + lr;
                    Cg[(long)row * 2048 + col] = f2bf(acc[qr][rf][cf][r]);
                }
            }
}

// ============ pipelined 128x128 GEMM (coupling / out_proj; N=512) ============
template<int NT>
__global__ __launch_bounds__(1024) void gemm_p128(
    const __hip_bfloat16* __restrict__ A_, const __hip_bfloat16* __restrict__ B_,
    int lda, int ldb, long sA, long sB,
    float* __restrict__ Cf, __hip_bfloat16* __restrict__ Cb, int ldc, long sC,
    const float* __restrict__ res, const float* __restrict__ resB,
    const float* __restrict__ resC,
    const __hip_bfloat16* __restrict__ resbf, long sResb,
    const float* __restrict__ coef_base)
{
    __shared__ alignas(16) short As[2 * 8192];
    __shared__ alignas(16) short Bs[2 * 8192];
    const int z = blockIdx.z;
    const int bm0 = blockIdx.x * 128;
    const int bn0 = blockIdx.y * 128;
    const short* Ag = (const short*)A_ + (long)z * sA + (long)bm0 * lda;
    const short* Bg = (const short*)B_ + (long)z * sB + (long)bn0 * ldb;
    const int tid = threadIdx.x;
    const int lane = tid & 63;
    const int w = tid >> 6;
    const int wr = w >> 2;
    const int wc = w & 3;
    const int lr = lane & 15;
    const int sidx = lane >> 4;
    const int srow_l = tid >> 3;
    const int sgoff = ((tid & 7) ^ (srow_l & 7)) * 8;

    f32x4 acc[2][2];
    #pragma unroll
    for (int a = 0; a < 2; ++a)
        #pragma unroll
        for (int b = 0; b < 2; ++b)
            acc[a][b] = (f32x4){0.f, 0.f, 0.f, 0.f};

    short8v afr[2][2];
    short8v bfr[2][2];

    auto stageA = [&](int buf, int t) {
        gl_lds16(Ag + (long)srow_l * lda + t * 64 + sgoff, As + buf * 8192 + tid * 8);
    };
    auto stageB = [&](int buf, int t) {
        gl_lds16(Bg + (long)srow_l * ldb + t * 64 + sgoff, Bs + buf * 8192 + tid * 8);
    };
    auto loadAB = [&](int buf) {
        #pragma unroll
        for (int rf = 0; rf < 2; ++rf)
            #pragma unroll
            for (int kh = 0; kh < 2; ++kh) {
                const int ra = wr * 32 + rf * 16 + lr;
                const int g = kh * 4 + sidx;
                afr[rf][kh] = *(const short8v*)&As[buf * 8192 + ra * 64 + ((g ^ (ra & 7)) << 3)];
            }
        #pragma unroll
        for (int cf = 0; cf < 2; ++cf)
            #pragma unroll
            for (int kh = 0; kh < 2; ++kh) {
                const int rb = wc * 32 + cf * 16 + lr;
                const int g = kh * 4 + sidx;
                bfr[cf][kh] = *(const short8v*)&Bs[buf * 8192 + rb * 64 + ((g ^ (rb & 7)) << 3)];
            }
    };

    stageA(0, 0); stageB(0, 0);

    for (int t = 0; t < NT; ++t) {
        const int p = t & 1;
        const bool stg = (t + 1) < NT;
        if (stg) { stageA(p ^ 1, t + 1); stageB(p ^ 1, t + 1);
                   asm volatile("s_waitcnt vmcnt(2)" ::: "memory"); }
        else       asm volatile("s_waitcnt vmcnt(0)" ::: "memory");
        asm volatile("s_barrier" ::: "memory");
        loadAB(p);
        #pragma unroll
        for (int rf = 0; rf < 2; ++rf)
            #pragma unroll
            for (int cf = 0; cf < 2; ++cf)
                #pragma unroll
                for (int kh = 0; kh < 2; ++kh)
                    acc[rf][cf] = __builtin_amdgcn_mfma_f32_16x16x32_bf16(
                        afr[rf][kh], bfr[cf][kh], acc[rf][cf], 0, 0, 0);
        asm volatile("s_barrier" ::: "memory");
    }

    const float alpha = coef_base ? coef_base[z] : 1.0f;
    const float* resz = res ? ((z == 0) ? res : ((z == 1) ? resB : resC)) : nullptr;
    const short* resbz = resbf ? (const short*)resbf + (long)z * sResb : nullptr;
    float* Cfz = Cf ? Cf + (long)z * sC : nullptr;
    short* Cbz = Cb ? (short*)Cb + (long)z * sC : nullptr;
    #pragma unroll
    for (int rf = 0; rf < 2; ++rf)
        #pragma unroll
        for (int r = 0; r < 4; ++r) {
            const int row = bm0 + wr * 32 + rf * 16 + (lane >> 4) * 4 + r;
            #pragma unroll
            for (int cf = 0; cf < 2; ++cf) {
                const int col = bn0 + wc * 32 + cf * 16 + lr;
                float val = acc[rf][cf][r] * alpha;
                if (resz)  val += resz[(long)row * ldc + col];
                if (resbz) val += bf2f(resbz[(long)row * ldc + col]);
                if (Cfz) Cfz[(long)row * ldc + col] = val;
                else     Cbz[(long)row * ldc + col] = f2bf(val);
            }
        }
}

// ---------------- bf16 MFMA GEMM NT, XOR-swizzled LDS, 2-phase prefetch dbuf ----------
template<int NJ, int BK>
__global__ __launch_bounds__(256) void gemm_bf16(
    const __hip_bfloat16* __restrict__ A_, const __hip_bfloat16* __restrict__ B_,
    int K, int lda, int ldb, long sA, long sB,
    float* __restrict__ Cf, __hip_bfloat16* __restrict__ Cb, int ldc, long sC,
    const float* __restrict__ res, long sRes,
    const float* __restrict__ resB, const float* __restrict__ resC,
    const __hip_bfloat16* __restrict__ resbf, long sResb,
    const float* __restrict__ coef_base, int coef_stride,
    const float* __restrict__ bias, long sBias, int act)
{
    constexpr int BN = NJ * 32;
    constexpr int ASZ = 128 * BK;
    constexpr int BSZe = BN * BK;
    __shared__ alignas(16) short As[2 * ASZ];
    __shared__ alignas(16) short Bs[2 * BSZe];
    const int z = blockIdx.z;
    const int bm0 = blockIdx.x * 128;
    const int bn0 = blockIdx.y * BN;
    const short* Ag = (const short*)A_ + z * sA + (long)bm0 * lda;
    const short* Bg = (const short*)B_ + z * sB + (long)bn0 * ldb;
    const int tid = threadIdx.x;
    const int lane = tid & 63;
    const int w = tid >> 6;
    const int wr = w >> 1, wc = w & 1;
    const int lr = lane & 15;
    const int sidx = lane >> 4;

    constexpr int SLOTS = BK / 8;
    const int srow = tid / SLOTS;
    const int sslot = tid % SLOTS;
    int swz;
    if constexpr (BK == 64) swz = srow & 7;
    else                    swz = (srow >> 1) & 3;
    const int sgcol = (sslot ^ swz) * 8;
    int fA;
    if constexpr (BK == 64) fA = lr & 7;
    else                    fA = (lr >> 1) & 3;

    constexpr int AINSTR = ASZ / 2048;
    constexpr int BINSTR = BSZe / 2048;
    constexpr int RPI = 2048 / BK;

    f32x4 acc[4][NJ];
    #pragma unroll
    for (int i = 0; i < 4; ++i)
        #pragma unroll
        for (int j = 0; j < NJ; ++j)
            acc[i][j] = (f32x4){0.f, 0.f, 0.f, 0.f};

    auto stage = [&](int buf, int k0) {
        #pragma unroll
        for (int i = 0; i < AINSTR; ++i)
            gl_lds16(Ag + (long)(i * RPI + srow) * lda + k0 + sgcol,
                     As + buf * ASZ + i * 2048 + tid * 8);
        #pragma unroll
        for (int i = 0; i < BINSTR; ++i)
            gl_lds16(Bg + (long)(i * RPI + srow) * ldb + k0 + sgcol,
                     Bs + buf * BSZe + i * 2048 + tid * 8);
    };
    auto compute = [&](int buf) {
        #pragma unroll
        for (int kh = 0; kh < BK / 32; ++kh) {
            const int sl = ((kh * 4 + sidx) ^ fA) * 8;
            short8v af[4], bfr2[NJ];
            #pragma unroll
            for (int i = 0; i < 4; ++i)
                af[i] = *(const short8v*)&As[buf * ASZ + (wr * 64 + i * 16 + lr) * BK + sl];
            #pragma unroll
            for (int j = 0; j < NJ; ++j)
                bfr2[j] = *(const short8v*)&Bs[buf * BSZe + (wc * NJ * 16 + j * 16 + lr) * BK + sl];
            #pragma unroll
            for (int i = 0; i < 4; ++i)
                #pragma unroll
                for (int j = 0; j < NJ; ++j)
                    acc[i][j] = __builtin_amdgcn_mfma_f32_16x16x32_bf16(af[i], bfr2[j], acc[i][j], 0, 0, 0);
        }
    };

    stage(0, 0);
    __syncthreads();
    int cur = 0;
    for (int k0 = BK; k0 < K; k0 += BK) {
        stage(cur ^ 1, k0);
        compute(cur);
        __syncthreads();
        cur ^= 1;
    }
    compute(cur);

    const float alpha = coef_base ? coef_base[z * coef_stride] : 1.0f;
    const float* resz = nullptr;
    if (res) {
        if (resB) resz = (z == 0) ? res : ((z == 1) ? resB : resC);
        else      resz = res + z * sRes;
    }
    const short* resbz = resbf ? (const short*)resbf + (long)z * sResb : nullptr;
    const float* biasz = bias ? bias + z * sBias : nullptr;
    float* Cfz = Cf ? Cf + (long)z * sC : nullptr;
    __hip_bfloat16* Cbz = Cb ? Cb + (long)z * sC : nullptr;
    #pragma unroll
    for (int i = 0; i < 4; ++i) {
        #pragma unroll
        for (int r = 0; r < 4; ++r) {
            const int row = bm0 + wr * 64 + i * 16 + (lane >> 4) * 4 + r;
            #pragma unroll
            for (int j = 0; j < NJ; ++j) {
                const int col = bn0 + wc * NJ * 16 + j * 16 + lr;
                float val = acc[i][j][r];
                if (biasz) val += biasz[col];
                if (act == 1)
                    val = (val > 20.f) ? val : LN2 * __log2f(1.f + EXP2F(val * LOG2E));
                val *= alpha;
                if (resz)  val += resz[(long)row * ldc + col];
                if (resbz) val += bf2f(resbz[(long)row * ldc + col]);
                if (Cfz) Cfz[(long)row * ldc + col] = val;
                else     Cbz[(long)row * ldc + col] = __float2bfloat16(val);
            }
        }
    }
}

// ---------------- fused prep: sec->bf16 + weight cvts + conv-wT + A2T ----------------
__global__ __launch_bounds__(256) void prep_kernel(
    const float* __restrict__ a, const float* __restrict__ t, const float* __restrict__ v,
    __hip_bfloat16* __restrict__ sec_bf,
    const float* __restrict__ couple_w, __hip_bfloat16* __restrict__ cw_bf,
    const float* __restrict__ in_w, __hip_bfloat16* __restrict__ inw_bf,
    const float* __restrict__ xproj_w, __hip_bfloat16* __restrict__ xpw_bf,
    const float* __restrict__ dt_w, __hip_bfloat16* __restrict__ dtw_bf,
    const float* __restrict__ out_w, __hip_bfloat16* __restrict__ outw_bf,
    const float* __restrict__ conv_w, float* __restrict__ cwT,
    const float* __restrict__ A_log, float* __restrict__ A2T)
{
    long idx = (long)blockIdx.x * 256 + threadIdx.x;
    if (idx < 1572864) {
        const int m = (int)(idx >> 19);
        const long off = idx & 524287;
        const float* sec = (m == 0) ? a : (m == 1) ? t : v;
        float4 sv = ((const float4*)sec)[off];
        short4v s;
        s.x = f2bf(sv.x); s.y = f2bf(sv.y); s.z = f2bf(sv.z); s.w = f2bf(sv.w);
        ((short4v*)sec_bf)[idx] = s;
        return;
    }
    idx -= 1572864;
    if (idx < 1449984) {
        const float* s; __hip_bfloat16* d; long off = idx;
        if      (off < 196608)              { s = couple_w; d = cw_bf; }
        else if ((off -= 196608) < 786432)  { s = in_w;     d = inw_bf; }
        else if ((off -= 786432) < 49152)   { s = xproj_w;  d = xpw_bf; }
        else if ((off -= 49152) < 24576)    { s = dt_w;     d = dtw_bf; }
        else    { off -= 24576;               s = out_w;    d = outw_bf; }
        float4 vv = ((const float4*)s)[off];
        short4v o;
        o.x = f2bf(vv.x); o.y = f2bf(vv.y); o.z = f2bf(vv.z); o.w = f2bf(vv.w);
        ((short4v*)d)[off] = o;
        return;
    }
    idx -= 1449984;
    if (idx < 12288) {
        const int k = (int)(idx & 3);
        const int c = (int)((idx >> 2) & 1023);
        const int m = (int)(idx >> 12);
        cwT[(m * DCONV + k) * DINNER + c] = conv_w[idx];
        return;
    }
    idx -= 12288;
    if (idx < 49152) {
        const int c = (int)(idx & 1023);
        const int n = (int)((idx >> 10) & 15);
        const int m = (int)(idx >> 14);
        A2T[idx] = -EXP2F(A_log[((long)m * DINNER + c) * NSTATE + n] * LOG2E) * LOG2E;
    }
}

// ---------------- LayerNorm: bf16 in -> bf16 out ----------------
__global__ __launch_bounds__(256) void ln_kernel(const __hip_bfloat16* __restrict__ x,
                                                 __hip_bfloat16* __restrict__ xn,
                                                 const float* __restrict__ nw, const float* __restrict__ nb)
{
    const int row = blockIdx.x;
    const int m = row >> 12;
    const int tid = threadIdx.x;
    const short2v vv = *(const short2v*)((const short*)x + (long)row * DMODEL + tid * 2);
    const float vx = bf2f(vv.x), vy = bf2f(vv.y);
    float s = vx + vy;
    float sq = vx * vx + vy * vy;
    #pragma unroll
    for (int off = 32; off > 0; off >>= 1) {
        s  += __shfl_down(s, off);
        sq += __shfl_down(sq, off);
    }
    __shared__ float ws_s[4], ws_q[4];
    const int wid = tid >> 6, lane = tid & 63;
    if (lane == 0) { ws_s[wid] = s; ws_q[wid] = sq; }
    __syncthreads();
    if (tid == 0) {
        float ts = ws_s[0] + ws_s[1] + ws_s[2] + ws_s[3];
        float tq = ws_q[0] + ws_q[1] + ws_q[2] + ws_q[3];
        float mu = ts / DMODEL;
        float var = tq / DMODEL - mu * mu;
        ws_s[0] = mu;
        ws_q[0] = rsqrtf(var + 1e-5f);
    }
    __syncthreads();
    const float mu = ws_s[0], rstd = ws_q[0];
    const int e0 = tid * 2;
    float2 w  = *reinterpret_cast<const float2*>(nw + m * DMODEL + e0);
    float2 bb = *reinterpret_cast<const float2*>(nb + m * DMODEL + e0);
    short2v o;
    o.x = f2bf((vx - mu) * rstd * w.x + bb.x);
    o.y = f2bf((vy - mu) * rstd * w.y + bb.y);
    *reinterpret_cast<short2v*>((short*)xn + (long)row * DMODEL + e0) = o;
}

// ---------------- depthwise causal conv(4) + SiLU ----------------
__global__ __launch_bounds__(256) void conv_silu_kernel(const __hip_bfloat16* __restrict__ xz,
    const float* __restrict__ cwT, const float* __restrict__ cb, __hip_bfloat16* __restrict__ xc)
{
    const int idx = blockIdx.x * 256 + threadIdx.x;   // < 6*256*128 = 196608
    const int c8 = idx & 127;
    const int lt = (idx >> 7) & 255;
    const int mb = idx >> 15;
    const int m  = mb >> 1;
    const int c0 = c8 * 8;
    const int l0 = lt * 8;

    float4 wlo[DCONV], whi[DCONV];
    #pragma unroll
    for (int k = 0; k < DCONV; ++k) {
        wlo[k] = *(const float4*)&cwT[(m * DCONV + k) * DINNER + c0];
        whi[k] = *(const float4*)&cwT[(m * DCONV + k) * DINNER + c0 + 4];
    }
    const float4 blo = *(const float4*)&cb[m * DINNER + c0];
    const float4 bhi = *(const float4*)&cb[m * DINNER + c0 + 4];

    const short* base = (const short*)xz + (long)mb * LSEQ * 2048 + c0;
    short* obase = (short*)xc + (long)mb * LSEQ * DINNER + c0;

    short8v r0 = {}, r1 = {}, r2 = {};
    if (l0 - 3 >= 0) r0 = *(const short8v*)(base + (long)(l0 - 3) * 2048);
    if (l0 - 2 >= 0) r1 = *(const short8v*)(base + (long)(l0 - 2) * 2048);
    if (l0 - 1 >= 0) r2 = *(const short8v*)(base + (long)(l0 - 1) * 2048);

    #pragma unroll
    for (int i = 0; i < 8; ++i) {
        const short8v cur = *(const short8v*)(base + (long)(l0 + i) * 2048);
        float acc[8];
        #pragma unroll
        for (int j = 0; j < 4; ++j) {
            acc[j]     = ((const float*)&blo)[j];
            acc[4 + j] = ((const float*)&bhi)[j];
        }
        #pragma unroll
        for (int j = 0; j < 8; ++j) {
            const float w0 = (j < 4) ? ((const float*)&wlo[0])[j] : ((const float*)&whi[0])[j - 4];
            const float w1 = (j < 4) ? ((const float*)&wlo[1])[j] : ((const float*)&whi[1])[j - 4];
            const float w2 = (j < 4) ? ((const float*)&wlo[2])[j] : ((const float*)&whi[2])[j - 4];
            const float w3 = (j < 4) ? ((const float*)&wlo[3])[j] : ((const float*)&whi[3])[j - 4];
            acc[j] += w0 * bf2f(r0[j]) + w1 * bf2f(r1[j]) + w2 * bf2f(r2[j]) + w3 * bf2f(cur[j]);
        }
        short8v o;
        #pragma unroll
        for (int j = 0; j < 8; ++j)
            o[j] = f2bf(acc[j] * sigmoid_f(acc[j]));
        *(short8v*)(obase + (long)(l0 + i) * DINNER) = o;
        r0 = r1; r1 = r2; r2 = cur;
    }
}

// ---------------- chunk-parallel selective scan: 2 channels/thread, CHUNK=16 ----------
__device__ __forceinline__ bool geo_check(const float* A2) {
    bool g = true;
    #pragma unroll
    for (int n = 1; n < NSTATE; ++n)
        g = g && (__builtin_fabsf(A2[n] - (float)(n + 1) * A2[0]) <= 1e-4f * __builtin_fabsf(A2[n]));
    return g;
}

// Pass 1: grid mb(6) x cg(2) x chunk(128) = 1536 blocks; F states stored bf16.
__global__ __launch_bounds__(256) void scan_pass1_kernel(
    const __hip_bfloat16* __restrict__ delta, const __hip_bfloat16* __restrict__ xc,
    const __hip_bfloat16* __restrict__ dbc, const float* __restrict__ A2T,
    __hip_bfloat16* __restrict__ Fbuf, float* __restrict__ sumd)
{
    const int bx = blockIdx.x;
    const int chunk = bx & (NCHUNK - 1);
    const int cg = (bx / NCHUNK) & 1;
    const int mb = bx / (2 * NCHUNK);
    const int m = mb >> 1, b = mb & 1;
    const int tid = threadIdx.x;
    const int c0 = cg * 256 + tid;
    const int c1 = c0 + 512;

    float A2a[NSTATE], A2b[NSTATE];
    #pragma unroll
    for (int n = 0; n < NSTATE; ++n) {
        A2a[n] = A2T[((long)m * NSTATE + n) * DINNER + c0];
        A2b[n] = A2T[((long)m * NSTATE + n) * DINNER + c1];
    }
    const bool geo = geo_check(A2a) && geo_check(A2b);
    float h0[NSTATE] = {}, h1[NSTATE] = {};
    float sd0 = 0.f, sd1 = 0.f;

    __shared__ float sB[CHUNK][NSTATE];
    const short* dbc_mb = (const short*)dbc + (long)m * MROWS * 64 + (long)b * LSEQ * 64;
    const int t0 = chunk * CHUNK;
    for (int i = tid; i < CHUNK * NSTATE; i += 256) {
        int tt = i >> 4, j = i & 15;
        sB[tt][j] = bf2f(dbc_mb[(long)(t0 + tt) * 64 + 32 + j]);
    }
    __syncthreads();

    const short* dp = (const short*)delta;
    const short* up = (const short*)xc;
    const long base = ((long)mb * LSEQ + t0) * DINNER + c0;
    if (geo) {
        #pragma unroll 2
        for (int tt = 0; tt < CHUNK; ++tt) {
            const long ix = base + (long)tt * DINNER;
            const float d0 = bf2f(dp[ix]),       u0 = bf2f(up[ix]);
            const float d1 = bf2f(dp[ix + 512]), u1 = bf2f(up[ix + 512]);
            const float du0 = d0 * u0, du1 = d1 * u1;
            sd0 += d0; sd1 += d1;
            const float E0 = EXP2F(d0 * A2a[0]);
            const float E1 = EXP2F(d1 * A2b[0]);
            float e0 = 1.f, e1 = 1.f;
            #pragma unroll
            for (int n = 0; n < NSTATE; ++n) {
                e0 *= E0; e1 *= E1;
                h0[n] = e0 * h0[n] + du0 * sB[tt][n];
                h1[n] = e1 * h1[n] + du1 * sB[tt][n];
            }
        }
    } else {
        #pragma unroll 2
        for (int tt = 0; tt < CHUNK; ++tt) {
            const long ix = base + (long)tt * DINNER;
            const float d0 = bf2f(dp[ix]),       u0 = bf2f(up[ix]);
            const float d1 = bf2f(dp[ix + 512]), u1 = bf2f(up[ix + 512]);
            const float du0 = d0 * u0, du1 = d1 * u1;
            sd0 += d0; sd1 += d1;
            #pragma unroll
            for (int n = 0; n < NSTATE; ++n) {
                h0[n] = EXP2F(d0 * A2a[n]) * h0[n] + du0 * sB[tt][n];
                h1[n] = EXP2F(d1 * A2b[n]) * h1[n] + du1 * sB[tt][n];
            }
        }
    }
    short* Fp = (short*)Fbuf;
    const long ob = ((long)mb * NCHUNK + chunk) * (NSTATE * DINNER) + c0;
    #pragma unroll
    for (int n = 0; n < NSTATE; ++n) {
        Fp[ob + n * DINNER] = f2bf(h0[n]);
        Fp[ob + n * DINNER + 512] = f2bf(h1[n]);
    }
    const long so = (((long)mb * NCHUNK + chunk) << 10) + c0;
    sumd[so] = sd0;
    sumd[so + 512] = sd1;
}

// Pass 2: sequential chunk combine over 128 chunks; F in bf16 (run accumulated f32).
__global__ __launch_bounds__(256) void scan_pass2_kernel(__hip_bfloat16* __restrict__ Fbuf,
                                                         const float* __restrict__ sumd,
                                                         const float* __restrict__ A2T)
{
    const long idx = (long)blockIdx.x * 256 + threadIdx.x;  // < 6*16*1024
    const int mb = (int)(idx >> 14);
    const int cn = (int)(idx & 16383);
    const int n = cn >> 10;
    const int c = cn & 1023;
    const int m = mb >> 1;
    const float A2n = A2T[((long)m * NSTATE + n) * DINNER + c];
    short* Fp = (short*)Fbuf;
    float run = 0.f;
    #pragma unroll 4
    for (int k = 0; k < NCHUNK; ++k) {
        const long o = ((long)(mb * NCHUNK + k) << 14) + cn;
        const float f = bf2f(Fp[o]);
        const float p = EXP2F(sumd[(((long)mb * NCHUNK + k) << 10) + c] * A2n);
        Fp[o] = f2bf(run);
        run = p * run + f;
    }
}

// Pass 3: grid 1536 blocks; h_in read from bf16 F.
__global__ __launch_bounds__(256) void scan_pass3_kernel(
    const __hip_bfloat16* __restrict__ delta, const __hip_bfloat16* __restrict__ xc,
    const __hip_bfloat16* __restrict__ dbc, __hip_bfloat16* __restrict__ xz,
    const float* __restrict__ A2T, const float* __restrict__ D_skip,
    const __hip_bfloat16* __restrict__ Hin)
{
    const int bx = blockIdx.x;
    const int chunk = bx & (NCHUNK - 1);
    const int cg = (bx / NCHUNK) & 1;
    const int mb = bx / (2 * NCHUNK);
    const int m = mb >> 1, b = mb & 1;
    const int tid = threadIdx.x;
    const int c0 = cg * 256 + tid;
    const int c1 = c0 + 512;

    float A2a[NSTATE], A2b[NSTATE];
    #pragma unroll
    for (int n = 0; n < NSTATE; ++n) {
        A2a[n] = A2T[((long)m * NSTATE + n) * DINNER + c0];
        A2b[n] = A2T[((long)m * NSTATE + n) * DINNER + c1];
    }
    const bool geo = geo_check(A2a) && geo_check(A2b);
    const float Dsk0 = D_skip[m * DINNER + c0];
    const float Dsk1 = D_skip[m * DINNER + c1];

    float h0[NSTATE], h1[NSTATE];
    const short* Hp = (const short*)Hin;
    const long ho = ((long)mb * NCHUNK + chunk) * (NSTATE * DINNER) + c0;
    #pragma unroll
    for (int n = 0; n < NSTATE; ++n) {
        h0[n] = bf2f(Hp[ho + n * DINNER]);
        h1[n] = bf2f(Hp[ho + n * DINNER + 512]);
    }

    __shared__ float sBC[CHUNK][2 * NSTATE];
    const short* dbc_mb = (const short*)dbc + (long)m * MROWS * 64 + (long)b * LSEQ * 64;
    const int t0 = chunk * CHUNK;
    for (int i = tid; i < CHUNK * 2 * NSTATE; i += 256) {
        int tt = i >> 5, j = i & 31;
        sBC[tt][j] = bf2f(dbc_mb[(long)(t0 + tt) * 64 + 32 + j]);
    }
    __syncthreads();

    const short* dp = (const short*)delta;
    const short* up = (const short*)xc;
    short* xzp = (short*)xz;
    const long base = ((long)mb * LSEQ + t0) * DINNER + c0;
    const long xbase = ((long)mb * LSEQ + t0) * 2048 + c0;
    if (geo) {
        #pragma unroll 2
        for (int tt = 0; tt < CHUNK; ++tt) {
            const long ix = base + (long)tt * DINNER;
            const long xi = xbase + (long)tt * 2048;
            const float d0 = bf2f(dp[ix]),       u0 = bf2f(up[ix]);
            const float d1 = bf2f(dp[ix + 512]), u1 = bf2f(up[ix + 512]);
            const float zv0 = bf2f(xzp[xi + 1024]);
            const float zv1 = bf2f(xzp[xi + 1536]);
            const float du0 = d0 * u0, du1 = d1 * u1;
            const float E0 = EXP2F(d0 * A2a[0]);
            const float E1 = EXP2F(d1 * A2b[0]);
            float e0 = 1.f, e1 = 1.f;
            float y0 = 0.f, y1 = 0.f;
            #pragma unroll
            for (int n = 0; n < NSTATE; ++n) {
                e0 *= E0; e1 *= E1;
                h0[n] = e0 * h0[n] + du0 * sBC[tt][n];
                h1[n] = e1 * h1[n] + du1 * sBC[tt][n];
                y0 += h0[n] * sBC[tt][16 + n];
                y1 += h1[n] * sBC[tt][16 + n];
            }
            y0 += u0 * Dsk0;
            y1 += u1 * Dsk1;
            xzp[xi]       = f2bf(y0 * (zv0 * sigmoid_f(zv0)));
            xzp[xi + 512] = f2bf(y1 * (zv1 * sigmoid_f(zv1)));
        }
    } else {
        #pragma unroll 2
        for (int tt = 0; tt < CHUNK; ++tt) {
            const long ix = base + (long)tt * DINNER;
            const long xi = xbase + (long)tt * 2048;
            const float d0 = bf2f(dp[ix]),       u0 = bf2f(up[ix]);
            const float d1 = bf2f(dp[ix + 512]), u1 = bf2f(up[ix + 512]);
            const float zv0 = bf2f(xzp[xi + 1024]);
            const float zv1 = bf2f(xzp[xi + 1536]);
            const float du0 = d0 * u0, du1 = d1 * u1;
            float y0 = 0.f, y1 = 0.f;
            #pragma unroll
            for (int n = 0; n < NSTATE; ++n) {
                h0[n] = EXP2F(d0 * A2a[n]) * h0[n] + du0 * sBC[tt][n];
                h1[n] = EXP2F(d1 * A2b[n]) * h1[n] + du1 * sBC[tt][n];
                y0 += h0[n] * sBC[tt][16 + n];
                y1 += h1[n] * sBC[tt][16 + n];
            }
            y0 += u0 * Dsk0;
            y1 += u1 * Dsk1;
            xzp[xi]       = f2bf(y0 * (zv0 * sigmoid_f(zv0)));
            xzp[xi + 512] = f2bf(y1 * (zv1 * sigmoid_f(zv1)));
        }
    }
}

extern "C" void kernel_launch(void* const* d_in, const int* in_sizes, int n_in,
                              void* d_out, int out_size, void* d_ws, size_t ws_size,
                              hipStream_t stream)
{
    const float* v       = (const float*)d_in[0];
    const float* a       = (const float*)d_in[1];
    const float* t       = (const float*)d_in[2];
    const float* norm_w  = (const float*)d_in[3];
    const float* norm_b  = (const float*)d_in[4];
    const float* in_w    = (const float*)d_in[5];
    const float* conv_w  = (const float*)d_in[6];
    const float* conv_b  = (const float*)d_in[7];
    const float* xproj_w = (const float*)d_in[8];
    const float* dt_w    = (const float*)d_in[9];
    const float* dt_b    = (const float*)d_in[10];
    const float* A_log   = (const float*)d_in[11];
    const float* D_skip  = (const float*)d_in[12];
    const float* out_w   = (const float*)d_in[13];
    const float* couple_w= (const float*)d_in[14];
    const float* coef    = (const float*)d_in[15];
    float* out = (float*)d_out;

    typedef __hip_bfloat16 bf;
    float* ws0    = (float*)d_ws;
    bf* x_in_bf   = (bf*)ws0;                           // [3][4096][512] bf16
    bf* xn_bf     = (bf*)(ws0 + 6291456);               // [3][4096][512]
    bf* sec_bf    = xn_bf + 6291456;                    // [3][4096][512]
    bf* xz_bf     = sec_bf + 6291456;                   // [3][4096][2048]  (xc-pre | z; later y | z)
    bf* xc_bf     = xz_bf + 25165824;                   // [3][4096][1024]
    bf* delta_bf  = xc_bf + 12582912;                   // [3][4096][1024]
    bf* dbc_bf    = delta_bf + 12582912;                // [3][4096][64]
    bf* cw_bf     = dbc_bf + 786432;                    // [3][512][512]
    bf* inw_bf    = cw_bf + 786432;                     // [3][2048][512]
    bf* xpw_bf    = inw_bf + 3145728;                   // [3][64][1024]
    bf* dtw_bf    = xpw_bf + 196608;                    // [3][1024][32]
    bf* outw_bf   = dtw_bf + 98304;                     // [3][512][1024]
    float* cwT    = (float*)(outw_bf + 1572864);        // [3][4][1024] f32
    float* A2T    = cwT + 12288;                        // [3][16][1024] f32
    bf* Fbuf      = (bf*)(A2T + 49152);                 // [6][128][16][1024] bf16
    float* sumd   = (float*)(Fbuf + 12582912);          // [6][128][1024] f32

    dim3 blk(256);

    // 0. fused prep
    prep_kernel<<<(1572864 + 1449984 + 12288 + 49152 + 255) / 256, blk, 0, stream>>>(
        a, t, v, sec_bf, couple_w, cw_bf, in_w, inw_bf, xproj_w, xpw_bf,
        dt_w, dtw_bf, out_w, outw_bf, conv_w, cwT, A_log, A2T);

    // 1. coupling (pipelined 128x128, 384 blocks co-resident)
    gemm_p128<8><<<dim3(32, 4, 3), 1024, 0, stream>>>(
        sec_bf, cw_bf, 512, 512, 2097152L, 262144L,
        nullptr, x_in_bf, 512, 2097152L,
        v, a, t, nullptr, 0L, coef);
    // 2. layernorm (bf16 in) -> bf16
    ln_kernel<<<3*4096, blk, 0, stream>>>(x_in_bf, xn_bf, norm_w, norm_b);
    // 3. in_proj -> xz  — pipelined 256x128, 768 blocks
    gemm8p_inproj<<<dim3(16, 16, 3), 1024, 0, stream>>>(xn_bf, inw_bf, xz_bf);
    // 4. conv + SiLU
    conv_silu_kernel<<<768, blk, 0, stream>>>(xz_bf, cwT, conv_b, xc_bf);
    // 5. x_proj -> dbc bf16 (BK=64, N=64 path)
    gemm_bf16<2, 64><<<dim3(32, 1, 3), blk, 0, stream>>>(
        xc_bf, xpw_bf, 1024, 1024, 1024, 4194304L, 65536L,
        nullptr, dbc_bf, 64, 262144L, nullptr, 0L, nullptr, nullptr, nullptr, 0L,
        nullptr, 0, nullptr, 0L, 0);
    // 6. delta = softplus(dt @ dt_w^T + dt_b) -> bf16
    gemm_bf16<4, 32><<<dim3(32, 8, 3), blk, 0, stream>>>(
        dbc_bf, dtw_bf, 32, 64, 32, 262144L, 32768L,
        nullptr, delta_bf, 1024, 4194304L, nullptr, 0L, nullptr, nullptr, nullptr, 0L,
        nullptr, 0, dt_b, 1024L, 1);
    // 7. chunk-parallel scan (2 channels/thread, 128 chunks of 16)
    scan_pass1_kernel<<<6*2*NCHUNK, blk, 0, stream>>>(delta_bf, xc_bf, dbc_bf, A2T, Fbuf, sumd);
    scan_pass2_kernel<<<(6*1024*16)/256, blk, 0, stream>>>(Fbuf, sumd, A2T);
    scan_pass3_kernel<<<6*2*NCHUNK, blk, 0, stream>>>(delta_bf, xc_bf, dbc_bf, xz_bf,
                                                      A2T, D_skip, Fbuf);
    // 8. out_proj + bf16 residual -> d_out (pipelined 128x128, K=1024)
    gemm_p128<16><<<dim3(32, 4, 3), 1024, 0, stream>>>(
        xz_bf, outw_bf, 2048, 1024, 8388608L, 524288L,
        out, nullptr, 512, 2097152L,
        nullptr, nullptr, nullptr, x_in_bf, 2097152L, nullptr);
}

// Round 25
// 227.764 us; speedup vs baseline: 1.0195x; 1.0195x over previous
//
#include <hip/hip_runtime.h>
#include <hip/hip_bf16.h>

#define MODS 3
#define BSZ 2
#define LSEQ 2048
#define DMODEL 512
#define DINNER 1024
#define DTRANK 32
#define NSTATE 16
#define DCONV 4
#define MROWS (BSZ*LSEQ)   // 4096
#define NCHUNK 64
#define CHUNK 32           // LSEQ / NCHUNK

#define LOG2E 1.44269504088896f
#define LN2   0.69314718055995f

typedef __attribute__((ext_vector_type(8))) short short8v;
typedef __attribute__((ext_vector_type(4))) short short4v;
typedef __attribute__((ext_vector_type(2))) short short2v;
typedef __attribute__((ext_vector_type(4))) float f32x4;

#if __has_builtin(__builtin_amdgcn_exp2f)
#define EXP2F __builtin_amdgcn_exp2f
#else
#define EXP2F exp2f
#endif
#if __has_builtin(__builtin_amdgcn_rcpf)
#define RCPF __builtin_amdgcn_rcpf
#else
#define RCPF(x) (1.0f / (x))
#endif

__device__ __forceinline__ short f2bf(float x) {
    __hip_bfloat16 h = __float2bfloat16(x);
    return __builtin_bit_cast(short, h);
}
__device__ __forceinline__ float bf2f(short s) {
    return __uint_as_float(((unsigned)(unsigned short)s) << 16);
}
__device__ __forceinline__ void gl_lds16(const short* g, short* l) {
    __builtin_amdgcn_global_load_lds(
        (const __attribute__((address_space(1))) unsigned int*)g,
        (__attribute__((address_space(3))) unsigned int*)l, 16, 0, 0);
}
__device__ __forceinline__ float sigmoid_f(float x) {
    return RCPF(1.f + EXP2F(-x * LOG2E));
}

// ============ pipelined 256x128 GEMM for in_proj (M=4096,N=2048,K=512) ============
#define MFMAQ(QR)                                                                  \
    _Pragma("unroll")                                                              \
    for (int rf = 0; rf < 2; ++rf)                                                 \
        _Pragma("unroll")                                                          \
        for (int cf = 0; cf < 2; ++cf)                                             \
            _Pragma("unroll")                                                      \
            for (int kh = 0; kh < 2; ++kh)                                         \
                acc[QR][rf][cf] = __builtin_amdgcn_mfma_f32_16x16x32_bf16(         \
                    afr[rf][kh], bfr[cf][kh], acc[QR][rf][cf], 0, 0, 0);

__global__ __launch_bounds__(1024) void gemm8p_inproj(
    const __hip_bfloat16* __restrict__ A_, const __hip_bfloat16* __restrict__ B_,
    __hip_bfloat16* __restrict__ C_)
{
    constexpr int NT = 8;                 // K=512 / BK=64
    __shared__ alignas(16) short As[2 * 16384];
    __shared__ alignas(16) short Bs[2 * 8192];
    const int z = blockIdx.z;
    const int bm0 = blockIdx.x * 256;
    const int bn0 = blockIdx.y * 128;
    const short* Ag = (const short*)A_ + (long)z * 2097152 + (long)bm0 * 512;
    const short* Bg = (const short*)B_ + (long)z * 1048576 + (long)bn0 * 512;
    short* Cg = (short*)C_ + (long)z * 8388608;
    const int tid = threadIdx.x;
    const int lane = tid & 63;
    const int w = tid >> 6;
    const int wr = w >> 2;
    const int wc = w & 3;
    const int lr = lane & 15;
    const int sidx = lane >> 4;
    const int srow_l = tid >> 3;
    const int sgoff = ((tid & 7) ^ (srow_l & 7)) * 8;

    f32x4 acc[2][2][2];
    #pragma unroll
    for (int a = 0; a < 2; ++a)
        #pragma unroll
        for (int b = 0; b < 2; ++b)
            #pragma unroll
            for (int c = 0; c < 2; ++c)
                acc[a][b][c] = (f32x4){0.f, 0.f, 0.f, 0.f};

    short8v afr[2][2];
    short8v bfr[2][2];

    auto stageA = [&](int buf, int half, int t) {
        const int row = half * 128 + srow_l;
        gl_lds16(Ag + (long)row * 512 + t * 64 + sgoff,
                 As + buf * 16384 + half * 8192 + tid * 8);
    };
    auto stageB = [&](int buf, int t) {
        const int row = srow_l;
        gl_lds16(Bg + (long)row * 512 + t * 64 + sgoff,
                 Bs + buf * 8192 + tid * 8);
    };
    auto loadA = [&](int buf, int qr) {
        #pragma unroll
        for (int rf = 0; rf < 2; ++rf)
            #pragma unroll
            for (int kh = 0; kh < 2; ++kh) {
                const int ra = qr * 128 + wr * 32 + rf * 16 + lr;
                const int g = kh * 4 + sidx;
                afr[rf][kh] = *(const short8v*)&As[buf * 16384 + ra * 64 + ((g ^ (ra & 7)) << 3)];
            }
    };
    auto loadB = [&](int buf) {
        #pragma unroll
        for (int cf = 0; cf < 2; ++cf)
            #pragma unroll
            for (int kh = 0; kh < 2; ++kh) {
                const int rb = wc * 32 + cf * 16 + lr;
                const int g = kh * 4 + sidx;
                bfr[cf][kh] = *(const short8v*)&Bs[buf * 8192 + rb * 64 + ((g ^ (rb & 7)) << 3)];
            }
    };

    stageA(0, 0, 0); stageB(0, 0); stageA(0, 1, 0);

    for (int t = 0; t < NT; ++t) {
        const int p = t & 1;
        const bool stg = (t + 1) < NT;
        if (stg) { stageA(p ^ 1, 0, t + 1); stageB(p ^ 1, t + 1);
                   asm volatile("s_waitcnt vmcnt(3)" ::: "memory"); }
        else       asm volatile("s_waitcnt vmcnt(1)" ::: "memory");
        asm volatile("s_barrier" ::: "memory");
        loadA(p, 0); loadB(p);
        MFMAQ(0)
        asm volatile("s_barrier" ::: "memory");
        if (stg) { stageA(p ^ 1, 1, t + 1);
                   asm volatile("s_waitcnt vmcnt(3)" ::: "memory"); }
        else       asm volatile("s_waitcnt vmcnt(0)" ::: "memory");
        asm volatile("s_barrier" ::: "memory");
        loadA(p, 1);
        MFMAQ(1)
        asm volatile("s_barrier" ::: "memory");
    }

    #pragma unroll
    for (int qr = 0; qr < 2; ++qr)
        #pragma unroll
        for (int rf = 0; rf < 2; ++rf)
            #pragma unroll
            for (int r = 0; r < 4; ++r) {
                const int row = bm0 + qr * 128 + wr * 32 + rf * 16 + (lane >> 4) * 4 + r;
                #pragma unroll
                for (int cf = 0; cf < 2; ++cf) {
                    const int col = bn0 + wc * 32 + cf * 16 + lr;
                    Cg[(long)row * 2048 + col] = f2bf(acc[qr][rf][cf][r]);
                }
            }
}

// ============ pipelined 128x128 GEMM (coupling / out_proj; N=512) ============
template<int NT>
__global__ __launch_bounds__(1024) void gemm_p128(
    const __hip_bfloat16* __restrict__ A_, const __hip_bfloat16* __restrict__ B_,
    int lda, int ldb, long sA, long sB,
    float* __restrict__ Cf, __hip_bfloat16* __restrict__ Cb, int ldc, long sC,
    const float* __restrict__ res, const float* __restrict__ resB,
    const float* __restrict__ resC,
    const __hip_bfloat16* __restrict__ resbf, long sResb,
    const float* __restrict__ coef_base)
{
    __shared__ alignas(16) short As[2 * 8192];
    __shared__ alignas(16) short Bs[2 * 8192];
    const int z = blockIdx.z;
    const int bm0 = blockIdx.x * 128;
    const int bn0 = blockIdx.y * 128;
    const short* Ag = (const short*)A_ + (long)z * sA + (long)bm0 * lda;
    const short* Bg = (const short*)B_ + (long)z * sB + (long)bn0 * ldb;
    const int tid = threadIdx.x;
    const int lane = tid & 63;
    const int w = tid >> 6;
    const int wr = w >> 2;
    const int wc = w & 3;
    const int lr = lane & 15;
    const int sidx = lane >> 4;
    const int srow_l = tid >> 3;
    const int sgoff = ((tid & 7) ^ (srow_l & 7)) * 8;

    f32x4 acc[2][2];
    #pragma unroll
    for (int a = 0; a < 2; ++a)
        #pragma unroll
        for (int b = 0; b < 2; ++b)
            acc[a][b] = (f32x4){0.f, 0.f, 0.f, 0.f};

    short8v afr[2][2];
    short8v bfr[2][2];

    auto stageA = [&](int buf, int t) {
        gl_lds16(Ag + (long)srow_l * lda + t * 64 + sgoff, As + buf * 8192 + tid * 8);
    };
    auto stageB = [&](int buf, int t) {
        gl_lds16(Bg + (long)srow_l * ldb + t * 64 + sgoff, Bs + buf * 8192 + tid * 8);
    };
    auto loadAB = [&](int buf) {
        #pragma unroll
        for (int rf = 0; rf < 2; ++rf)
            #pragma unroll
            for (int kh = 0; kh < 2; ++kh) {
                const int ra = wr * 32 + rf * 16 + lr;
                const int g = kh * 4 + sidx;
                afr[rf][kh] = *(const short8v*)&As[buf * 8192 + ra * 64 + ((g ^ (ra & 7)) << 3)];
            }
        #pragma unroll
        for (int cf = 0; cf < 2; ++cf)
            #pragma unroll
            for (int kh = 0; kh < 2; ++kh) {
                const int rb = wc * 32 + cf * 16 + lr;
                const int g = kh * 4 + sidx;
                bfr[cf][kh] = *(const short8v*)&Bs[buf * 8192 + rb * 64 + ((g ^ (rb & 7)) << 3)];
            }
    };

    stageA(0, 0); stageB(0, 0);

    for (int t = 0; t < NT; ++t) {
        const int p = t & 1;
        const bool stg = (t + 1) < NT;
        if (stg) { stageA(p ^ 1, t + 1); stageB(p ^ 1, t + 1);
                   asm volatile("s_waitcnt vmcnt(2)" ::: "memory"); }
        else       asm volatile("s_waitcnt vmcnt(0)" ::: "memory");
        asm volatile("s_barrier" ::: "memory");
        loadAB(p);
        #pragma unroll
        for (int rf = 0; rf < 2; ++rf)
            #pragma unroll
            for (int cf = 0; cf < 2; ++cf)
                #pragma unroll
                for (int kh = 0; kh < 2; ++kh)
                    acc[rf][cf] = __builtin_amdgcn_mfma_f32_16x16x32_bf16(
                        afr[rf][kh], bfr[cf][kh], acc[rf][cf], 0, 0, 0);
        asm volatile("s_barrier" ::: "memory");
    }

    const float alpha = coef_base ? coef_base[z] : 1.0f;
    const float* resz = res ? ((z == 0) ? res : ((z == 1) ? resB : resC)) : nullptr;
    const short* resbz = resbf ? (const short*)resbf + (long)z * sResb : nullptr;
    float* Cfz = Cf ? Cf + (long)z * sC : nullptr;
    short* Cbz = Cb ? (short*)Cb + (long)z * sC : nullptr;
    #pragma unroll
    for (int rf = 0; rf < 2; ++rf)
        #pragma unroll
        for (int r = 0; r < 4; ++r) {
            const int row = bm0 + wr * 32 + rf * 16 + (lane >> 4) * 4 + r;
            #pragma unroll
            for (int cf = 0; cf < 2; ++cf) {
                const int col = bn0 + wc * 32 + cf * 16 + lr;
                float val = acc[rf][cf][r] * alpha;
                if (resz)  val += resz[(long)row * ldc + col];
                if (resbz) val += bf2f(resbz[(long)row * ldc + col]);
                if (Cfz) Cfz[(long)row * ldc + col] = val;
                else     Cbz[(long)row * ldc + col] = f2bf(val);
            }
        }
}

// ---------------- bf16 MFMA GEMM NT, XOR-swizzled LDS, 2-phase prefetch dbuf ----------
template<int NJ, int BK>
__global__ __launch_bounds__(256) void gemm_bf16(
    const __hip_bfloat16* __restrict__ A_, const __hip_bfloat16* __restrict__ B_,
    int K, int lda, int ldb, long sA, long sB,
    float* __restrict__ Cf, __hip_bfloat16* __restrict__ Cb, int ldc, long sC,
    const float* __restrict__ res, long sRes,
    const float* __restrict__ resB, const float* __restrict__ resC,
    const __hip_bfloat16* __restrict__ resbf, long sResb,
    const float* __restrict__ coef_base, int coef_stride,
    const float* __restrict__ bias, long sBias, int act)
{
    constexpr int BN = NJ * 32;
    constexpr int ASZ = 128 * BK;
    constexpr int BSZe = BN * BK;
    __shared__ alignas(16) short As[2 * ASZ];
    __shared__ alignas(16) short Bs[2 * BSZe];
    const int z = blockIdx.z;
    const int bm0 = blockIdx.x * 128;
    const int bn0 = blockIdx.y * BN;
    const short* Ag = (const short*)A_ + z * sA + (long)bm0 * lda;
    const short* Bg = (const short*)B_ + z * sB + (long)bn0 * ldb;
    const int tid = threadIdx.x;
    const int lane = tid & 63;
    const int w = tid >> 6;
    const int wr = w >> 1, wc = w & 1;
    const int lr = lane & 15;
    const int sidx = lane >> 4;

    constexpr int SLOTS = BK / 8;
    const int srow = tid / SLOTS;
    const int sslot = tid % SLOTS;
    int swz;
    if constexpr (BK == 64) swz = srow & 7;
    else                    swz = (srow >> 1) & 3;
    const int sgcol = (sslot ^ swz) * 8;
    int fA;
    if constexpr (BK == 64) fA = lr & 7;
    else                    fA = (lr >> 1) & 3;

    constexpr int AINSTR = ASZ / 2048;
    constexpr int BINSTR = BSZe / 2048;
    constexpr int RPI = 2048 / BK;

    f32x4 acc[4][NJ];
    #pragma unroll
    for (int i = 0; i < 4; ++i)
        #pragma unroll
        for (int j = 0; j < NJ; ++j)
            acc[i][j] = (f32x4){0.f, 0.f, 0.f, 0.f};

    auto stage = [&](int buf, int k0) {
        #pragma unroll
        for (int i = 0; i < AINSTR; ++i)
            gl_lds16(Ag + (long)(i * RPI + srow) * lda + k0 + sgcol,
                     As + buf * ASZ + i * 2048 + tid * 8);
        #pragma unroll
        for (int i = 0; i < BINSTR; ++i)
            gl_lds16(Bg + (long)(i * RPI + srow) * ldb + k0 + sgcol,
                     Bs + buf * BSZe + i * 2048 + tid * 8);
    };
    auto compute = [&](int buf) {
        #pragma unroll
        for (int kh = 0; kh < BK / 32; ++kh) {
            const int sl = ((kh * 4 + sidx) ^ fA) * 8;
            short8v af[4], bfr2[NJ];
            #pragma unroll
            for (int i = 0; i < 4; ++i)
                af[i] = *(const short8v*)&As[buf * ASZ + (wr * 64 + i * 16 + lr) * BK + sl];
            #pragma unroll
            for (int j = 0; j < NJ; ++j)
                bfr2[j] = *(const short8v*)&Bs[buf * BSZe + (wc * NJ * 16 + j * 16 + lr) * BK + sl];
            #pragma unroll
            for (int i = 0; i < 4; ++i)
                #pragma unroll
                for (int j = 0; j < NJ; ++j)
                    acc[i][j] = __builtin_amdgcn_mfma_f32_16x16x32_bf16(af[i], bfr2[j], acc[i][j], 0, 0, 0);
        }
    };

    stage(0, 0);
    __syncthreads();
    int cur = 0;
    for (int k0 = BK; k0 < K; k0 += BK) {
        stage(cur ^ 1, k0);
        compute(cur);
        __syncthreads();
        cur ^= 1;
    }
    compute(cur);

    const float alpha = coef_base ? coef_base[z * coef_stride] : 1.0f;
    const float* resz = nullptr;
    if (res) {
        if (resB) resz = (z == 0) ? res : ((z == 1) ? resB : resC);
        else      resz = res + z * sRes;
    }
    const short* resbz = resbf ? (const short*)resbf + (long)z * sResb : nullptr;
    const float* biasz = bias ? bias + z * sBias : nullptr;
    float* Cfz = Cf ? Cf + (long)z * sC : nullptr;
    __hip_bfloat16* Cbz = Cb ? Cb + (long)z * sC : nullptr;
    #pragma unroll
    for (int i = 0; i < 4; ++i) {
        #pragma unroll
        for (int r = 0; r < 4; ++r) {
            const int row = bm0 + wr * 64 + i * 16 + (lane >> 4) * 4 + r;
            #pragma unroll
            for (int j = 0; j < NJ; ++j) {
                const int col = bn0 + wc * NJ * 16 + j * 16 + lr;
                float val = acc[i][j][r];
                if (biasz) val += biasz[col];
                if (act == 1)
                    val = (val > 20.f) ? val : LN2 * __log2f(1.f + EXP2F(val * LOG2E));
                val *= alpha;
                if (resz)  val += resz[(long)row * ldc + col];
                if (resbz) val += bf2f(resbz[(long)row * ldc + col]);
                if (Cfz) Cfz[(long)row * ldc + col] = val;
                else     Cbz[(long)row * ldc + col] = __float2bfloat16(val);
            }
        }
    }
}

// ---------------- fused prep: sec->bf16 + weight cvts + conv-wT + A2T ----------------
__global__ __launch_bounds__(256) void prep_kernel(
    const float* __restrict__ a, const float* __restrict__ t, const float* __restrict__ v,
    __hip_bfloat16* __restrict__ sec_bf,
    const float* __restrict__ couple_w, __hip_bfloat16* __restrict__ cw_bf,
    const float* __restrict__ in_w, __hip_bfloat16* __restrict__ inw_bf,
    const float* __restrict__ xproj_w, __hip_bfloat16* __restrict__ xpw_bf,
    const float* __restrict__ dt_w, __hip_bfloat16* __restrict__ dtw_bf,
    const float* __restrict__ out_w, __hip_bfloat16* __restrict__ outw_bf,
    const float* __restrict__ conv_w, float* __restrict__ cwT,
    const float* __restrict__ A_log, float* __restrict__ A2T)
{
    long idx = (long)blockIdx.x * 256 + threadIdx.x;
    if (idx < 1572864) {
        const int m = (int)(idx >> 19);
        const long off = idx & 524287;
        const float* sec = (m == 0) ? a : (m == 1) ? t : v;
        float4 sv = ((const float4*)sec)[off];
        short4v s;
        s.x = f2bf(sv.x); s.y = f2bf(sv.y); s.z = f2bf(sv.z); s.w = f2bf(sv.w);
        ((short4v*)sec_bf)[idx] = s;
        return;
    }
    idx -= 1572864;
    if (idx < 1449984) {
        const float* s; __hip_bfloat16* d; long off = idx;
        if      (off < 196608)              { s = couple_w; d = cw_bf; }
        else if ((off -= 196608) < 786432)  { s = in_w;     d = inw_bf; }
        else if ((off -= 786432) < 49152)   { s = xproj_w;  d = xpw_bf; }
        else if ((off -= 49152) < 24576)    { s = dt_w;     d = dtw_bf; }
        else    { off -= 24576;               s = out_w;    d = outw_bf; }
        float4 vv = ((const float4*)s)[off];
        short4v o;
        o.x = f2bf(vv.x); o.y = f2bf(vv.y); o.z = f2bf(vv.z); o.w = f2bf(vv.w);
        ((short4v*)d)[off] = o;
        return;
    }
    idx -= 1449984;
    if (idx < 12288) {
        const int k = (int)(idx & 3);
        const int c = (int)((idx >> 2) & 1023);
        const int m = (int)(idx >> 12);
        cwT[(m * DCONV + k) * DINNER + c] = conv_w[idx];
        return;
    }
    idx -= 12288;
    if (idx < 49152) {
        const int c = (int)(idx & 1023);
        const int n = (int)((idx >> 10) & 15);
        const int m = (int)(idx >> 14);
        A2T[idx] = -EXP2F(A_log[((long)m * DINNER + c) * NSTATE + n] * LOG2E) * LOG2E;
    }
}

// ---------------- LayerNorm: bf16 in -> bf16 out ----------------
__global__ __launch_bounds__(256) void ln_kernel(const __hip_bfloat16* __restrict__ x,
                                                 __hip_bfloat16* __restrict__ xn,
                                                 const float* __restrict__ nw, const float* __restrict__ nb)
{
    const int row = blockIdx.x;
    const int m = row >> 12;
    const int tid = threadIdx.x;
    const short2v vv = *(const short2v*)((const short*)x + (long)row * DMODEL + tid * 2);
    const float vx = bf2f(vv.x), vy = bf2f(vv.y);
    float s = vx + vy;
    float sq = vx * vx + vy * vy;
    #pragma unroll
    for (int off = 32; off > 0; off >>= 1) {
        s  += __shfl_down(s, off);
        sq += __shfl_down(sq, off);
    }
    __shared__ float ws_s[4], ws_q[4];
    const int wid = tid >> 6, lane = tid & 63;
    if (lane == 0) { ws_s[wid] = s; ws_q[wid] = sq; }
    __syncthreads();
    if (tid == 0) {
        float ts = ws_s[0] + ws_s[1] + ws_s[2] + ws_s[3];
        float tq = ws_q[0] + ws_q[1] + ws_q[2] + ws_q[3];
        float mu = ts / DMODEL;
        float var = tq / DMODEL - mu * mu;
        ws_s[0] = mu;
        ws_q[0] = rsqrtf(var + 1e-5f);
    }
    __syncthreads();
    const float mu = ws_s[0], rstd = ws_q[0];
    const int e0 = tid * 2;
    float2 w  = *reinterpret_cast<const float2*>(nw + m * DMODEL + e0);
    float2 bb = *reinterpret_cast<const float2*>(nb + m * DMODEL + e0);
    short2v o;
    o.x = f2bf((vx - mu) * rstd * w.x + bb.x);
    o.y = f2bf((vy - mu) * rstd * w.y + bb.y);
    *reinterpret_cast<short2v*>((short*)xn + (long)row * DMODEL + e0) = o;
}

// ---------------- depthwise causal conv(4) + SiLU ----------------
__global__ __launch_bounds__(256) void conv_silu_kernel(const __hip_bfloat16* __restrict__ xz,
    const float* __restrict__ cwT, const float* __restrict__ cb, __hip_bfloat16* __restrict__ xc)
{
    const int idx = blockIdx.x * 256 + threadIdx.x;   // < 6*256*128 = 196608
    const int c8 = idx & 127;
    const int lt = (idx >> 7) & 255;
    const int mb = idx >> 15;
    const int m  = mb >> 1;
    const int c0 = c8 * 8;
    const int l0 = lt * 8;

    float4 wlo[DCONV], whi[DCONV];
    #pragma unroll
    for (int k = 0; k < DCONV; ++k) {
        wlo[k] = *(const float4*)&cwT[(m * DCONV + k) * DINNER + c0];
        whi[k] = *(const float4*)&cwT[(m * DCONV + k) * DINNER + c0 + 4];
    }
    const float4 blo = *(const float4*)&cb[m * DINNER + c0];
    const float4 bhi = *(const float4*)&cb[m * DINNER + c0 + 4];

    const short* base = (const short*)xz + (long)mb * LSEQ * 2048 + c0;
    short* obase = (short*)xc + (long)mb * LSEQ * DINNER + c0;

    short8v r0 = {}, r1 = {}, r2 = {};
    if (l0 - 3 >= 0) r0 = *(const short8v*)(base + (long)(l0 - 3) * 2048);
    if (l0 - 2 >= 0) r1 = *(const short8v*)(base + (long)(l0 - 2) * 2048);
    if (l0 - 1 >= 0) r2 = *(const short8v*)(base + (long)(l0 - 1) * 2048);

    #pragma unroll
    for (int i = 0; i < 8; ++i) {
        const short8v cur = *(const short8v*)(base + (long)(l0 + i) * 2048);
        float acc[8];
        #pragma unroll
        for (int j = 0; j < 4; ++j) {
            acc[j]     = ((const float*)&blo)[j];
            acc[4 + j] = ((const float*)&bhi)[j];
        }
        #pragma unroll
        for (int j = 0; j < 8; ++j) {
            const float w0 = (j < 4) ? ((const float*)&wlo[0])[j] : ((const float*)&whi[0])[j - 4];
            const float w1 = (j < 4) ? ((const float*)&wlo[1])[j] : ((const float*)&whi[1])[j - 4];
            const float w2 = (j < 4) ? ((const float*)&wlo[2])[j] : ((const float*)&whi[2])[j - 4];
            const float w3 = (j < 4) ? ((const float*)&wlo[3])[j] : ((const float*)&whi[3])[j - 4];
            acc[j] += w0 * bf2f(r0[j]) + w1 * bf2f(r1[j]) + w2 * bf2f(r2[j]) + w3 * bf2f(cur[j]);
        }
        short8v o;
        #pragma unroll
        for (int j = 0; j < 8; ++j)
            o[j] = f2bf(acc[j] * sigmoid_f(acc[j]));
        *(short8v*)(obase + (long)(l0 + i) * DINNER) = o;
        r0 = r1; r1 = r2; r2 = cur;
    }
}

// ---------------- chunk-parallel selective scan: 2 channels/thread for ILP ----------
__device__ __forceinline__ bool geo_check(const float* A2) {
    bool g = true;
    #pragma unroll
    for (int n = 1; n < NSTATE; ++n)
        g = g && (__builtin_fabsf(A2[n] - (float)(n + 1) * A2[0]) <= 1e-4f * __builtin_fabsf(A2[n]));
    return g;
}

__global__ __launch_bounds__(256) void scan_pass1_kernel(
    const __hip_bfloat16* __restrict__ delta, const __hip_bfloat16* __restrict__ xc,
    const __hip_bfloat16* __restrict__ dbc, const float* __restrict__ A2T,
    float* __restrict__ Fbuf, float* __restrict__ sumd)
{
    const int bx = blockIdx.x;
    const int chunk = bx & (NCHUNK - 1);
    const int cg = (bx >> 6) & 1;
    const int mb = bx >> 7;
    const int m = mb >> 1, b = mb & 1;
    const int tid = threadIdx.x;
    const int c0 = cg * 256 + tid;
    const int c1 = c0 + 512;

    float A2a[NSTATE], A2b[NSTATE];
    #pragma unroll
    for (int n = 0; n < NSTATE; ++n) {
        A2a[n] = A2T[((long)m * NSTATE + n) * DINNER + c0];
        A2b[n] = A2T[((long)m * NSTATE + n) * DINNER + c1];
    }
    const bool geo = geo_check(A2a) && geo_check(A2b);
    float h0[NSTATE] = {}, h1[NSTATE] = {};
    float sd0 = 0.f, sd1 = 0.f;

    __shared__ float sB[CHUNK][NSTATE];
    const short* dbc_mb = (const short*)dbc + (long)m * MROWS * 64 + (long)b * LSEQ * 64;
    const int t0 = chunk * CHUNK;
    for (int i = tid; i < CHUNK * NSTATE; i += 256) {
        int tt = i >> 4, j = i & 15;
        sB[tt][j] = bf2f(dbc_mb[(long)(t0 + tt) * 64 + 32 + j]);
    }
    __syncthreads();

    const short* dp = (const short*)delta;
    const short* up = (const short*)xc;
    const long base = ((long)mb * LSEQ + t0) * DINNER + c0;
    if (geo) {
        #pragma unroll 2
        for (int tt = 0; tt < CHUNK; ++tt) {
            const long ix = base + (long)tt * DINNER;
            const float d0 = bf2f(dp[ix]),       u0 = bf2f(up[ix]);
            const float d1 = bf2f(dp[ix + 512]), u1 = bf2f(up[ix + 512]);
            const float du0 = d0 * u0, du1 = d1 * u1;
            sd0 += d0; sd1 += d1;
            const float E0 = EXP2F(d0 * A2a[0]);
            const float E1 = EXP2F(d1 * A2b[0]);
            float e0 = 1.f, e1 = 1.f;
            #pragma unroll
            for (int n = 0; n < NSTATE; ++n) {
                e0 *= E0; e1 *= E1;
                h0[n] = e0 * h0[n] + du0 * sB[tt][n];
                h1[n] = e1 * h1[n] + du1 * sB[tt][n];
            }
        }
    } else {
        #pragma unroll 2
        for (int tt = 0; tt < CHUNK; ++tt) {
            const long ix = base + (long)tt * DINNER;
            const float d0 = bf2f(dp[ix]),       u0 = bf2f(up[ix]);
            const float d1 = bf2f(dp[ix + 512]), u1 = bf2f(up[ix + 512]);
            const float du0 = d0 * u0, du1 = d1 * u1;
            sd0 += d0; sd1 += d1;
            #pragma unroll
            for (int n = 0; n < NSTATE; ++n) {
                h0[n] = EXP2F(d0 * A2a[n]) * h0[n] + du0 * sB[tt][n];
                h1[n] = EXP2F(d1 * A2b[n]) * h1[n] + du1 * sB[tt][n];
            }
        }
    }
    const long ob = ((long)mb * NCHUNK + chunk) * (NSTATE * DINNER) + c0;
    #pragma unroll
    for (int n = 0; n < NSTATE; ++n) {
        Fbuf[ob + n * DINNER] = h0[n];
        Fbuf[ob + n * DINNER + 512] = h1[n];
    }
    const long so = (((long)mb * NCHUNK + chunk) << 10) + c0;
    sumd[so] = sd0;
    sumd[so + 512] = sd1;
}

__global__ __launch_bounds__(256) void scan_pass2_kernel(float* __restrict__ Fbuf,
                                                         const float* __restrict__ sumd,
                                                         const float* __restrict__ A2T)
{
    const long idx = (long)blockIdx.x * 256 + threadIdx.x;  // < 6*16*1024
    const int mb = (int)(idx >> 14);
    const int cn = (int)(idx & 16383);
    const int n = cn >> 10;
    const int c = cn & 1023;
    const int m = mb >> 1;
    const float A2n = A2T[((long)m * NSTATE + n) * DINNER + c];
    float run = 0.f;
    #pragma unroll 4
    for (int k = 0; k < NCHUNK; ++k) {
        const long o = ((long)(mb * NCHUNK + k) << 14) + cn;
        const float f = Fbuf[o];
        const float p = EXP2F(sumd[(((long)mb * NCHUNK + k) << 10) + c] * A2n);
        Fbuf[o] = run;
        run = p * run + f;
    }
}

__global__ __launch_bounds__(256) void scan_pass3_kernel(
    const __hip_bfloat16* __restrict__ delta, const __hip_bfloat16* __restrict__ xc,
    const __hip_bfloat16* __restrict__ dbc, __hip_bfloat16* __restrict__ xz,
    const float* __restrict__ A2T, const float* __restrict__ D_skip,
    const float* __restrict__ Hin)
{
    const int bx = blockIdx.x;
    const int chunk = bx & (NCHUNK - 1);
    const int cg = (bx >> 6) & 1;
    const int mb = bx >> 7;
    const int m = mb >> 1, b = mb & 1;
    const int tid = threadIdx.x;
    const int c0 = cg * 256 + tid;
    const int c1 = c0 + 512;

    float A2a[NSTATE], A2b[NSTATE];
    #pragma unroll
    for (int n = 0; n < NSTATE; ++n) {
        A2a[n] = A2T[((long)m * NSTATE + n) * DINNER + c0];
        A2b[n] = A2T[((long)m * NSTATE + n) * DINNER + c1];
    }
    const bool geo = geo_check(A2a) && geo_check(A2b);
    const float Dsk0 = D_skip[m * DINNER + c0];
    const float Dsk1 = D_skip[m * DINNER + c1];

    float h0[NSTATE], h1[NSTATE];
    const long ho = ((long)mb * NCHUNK + chunk) * (NSTATE * DINNER) + c0;
    #pragma unroll
    for (int n = 0; n < NSTATE; ++n) {
        h0[n] = Hin[ho + n * DINNER];
        h1[n] = Hin[ho + n * DINNER + 512];
    }

    __shared__ float sBC[CHUNK][2 * NSTATE];
    const short* dbc_mb = (const short*)dbc + (long)m * MROWS * 64 + (long)b * LSEQ * 64;
    const int t0 = chunk * CHUNK;
    for (int i = tid; i < CHUNK * 2 * NSTATE; i += 256) {
        int tt = i >> 5, j = i & 31;
        sBC[tt][j] = bf2f(dbc_mb[(long)(t0 + tt) * 64 + 32 + j]);
    }
    __syncthreads();

    const short* dp = (const short*)delta;
    const short* up = (const short*)xc;
    short* xzp = (short*)xz;
    const long base = ((long)mb * LSEQ + t0) * DINNER + c0;
    const long xbase = ((long)mb * LSEQ + t0) * 2048 + c0;
    if (geo) {
        #pragma unroll 2
        for (int tt = 0; tt < CHUNK; ++tt) {
            const long ix = base + (long)tt * DINNER;
            const long xi = xbase + (long)tt * 2048;
            const float d0 = bf2f(dp[ix]),       u0 = bf2f(up[ix]);
            const float d1 = bf2f(dp[ix + 512]), u1 = bf2f(up[ix + 512]);
            const float zv0 = bf2f(xzp[xi + 1024]);
            const float zv1 = bf2f(xzp[xi + 1536]);
            const float du0 = d0 * u0, du1 = d1 * u1;
            const float E0 = EXP2F(d0 * A2a[0]);
            const float E1 = EXP2F(d1 * A2b[0]);
            float e0 = 1.f, e1 = 1.f;
            float y0 = 0.f, y1 = 0.f;
            #pragma unroll
            for (int n = 0; n < NSTATE; ++n) {
                e0 *= E0; e1 *= E1;
                h0[n] = e0 * h0[n] + du0 * sBC[tt][n];
                h1[n] = e1 * h1[n] + du1 * sBC[tt][n];
                y0 += h0[n] * sBC[tt][16 + n];
                y1 += h1[n] * sBC[tt][16 + n];
            }
            y0 += u0 * Dsk0;
            y1 += u1 * Dsk1;
            xzp[xi]       = f2bf(y0 * (zv0 * sigmoid_f(zv0)));
            xzp[xi + 512] = f2bf(y1 * (zv1 * sigmoid_f(zv1)));
        }
    } else {
        #pragma unroll 2
        for (int tt = 0; tt < CHUNK; ++tt) {
            const long ix = base + (long)tt * DINNER;
            const long xi = xbase + (long)tt * 2048;
            const float d0 = bf2f(dp[ix]),       u0 = bf2f(up[ix]);
            const float d1 = bf2f(dp[ix + 512]), u1 = bf2f(up[ix + 512]);
            const float zv0 = bf2f(xzp[xi + 1024]);
            const float zv1 = bf2f(xzp[xi + 1536]);
            const float du0 = d0 * u0, du1 = d1 * u1;
            float y0 = 0.f, y1 = 0.f;
            #pragma unroll
            for (int n = 0; n < NSTATE; ++n) {
                h0[n] = EXP2F(d0 * A2a[n]) * h0[n] + du0 * sBC[tt][n];
                h1[n] = EXP2F(d1 * A2b[n]) * h1[n] + du1 * sBC[tt][n];
                y0 += h0[n] * sBC[tt][16 + n];
                y1 += h1[n] * sBC[tt][16 + n];
            }
            y0 += u0 * Dsk0;
            y1 += u1 * Dsk1;
            xzp[xi]       = f2bf(y0 * (zv0 * sigmoid_f(zv0)));
            xzp[xi + 512] = f2bf(y1 * (zv1 * sigmoid_f(zv1)));
        }
    }
}

extern "C" void kernel_launch(void* const* d_in, const int* in_sizes, int n_in,
                              void* d_out, int out_size, void* d_ws, size_t ws_size,
                              hipStream_t stream)
{
    const float* v       = (const float*)d_in[0];
    const float* a       = (const float*)d_in[1];
    const float* t       = (const float*)d_in[2];
    const float* norm_w  = (const float*)d_in[3];
    const float* norm_b  = (const float*)d_in[4];
    const float* in_w    = (const float*)d_in[5];
    const float* conv_w  = (const float*)d_in[6];
    const float* conv_b  = (const float*)d_in[7];
    const float* xproj_w = (const float*)d_in[8];
    const float* dt_w    = (const float*)d_in[9];
    const float* dt_b    = (const float*)d_in[10];
    const float* A_log   = (const float*)d_in[11];
    const float* D_skip  = (const float*)d_in[12];
    const float* out_w   = (const float*)d_in[13];
    const float* couple_w= (const float*)d_in[14];
    const float* coef    = (const float*)d_in[15];
    float* out = (float*)d_out;

    typedef __hip_bfloat16 bf;
    float* ws0    = (float*)d_ws;
    bf* x_in_bf   = (bf*)ws0;                           // [3][4096][512] bf16
    bf* xn_bf     = (bf*)(ws0 + 6291456);               // [3][4096][512]
    bf* sec_bf    = xn_bf + 6291456;                    // [3][4096][512]
    bf* xz_bf     = sec_bf + 6291456;                   // [3][4096][2048]  (xc-pre | z; later y | z)
    bf* xc_bf     = xz_bf + 25165824;                   // [3][4096][1024]
    bf* delta_bf  = xc_bf + 12582912;                   // [3][4096][1024]
    bf* dbc_bf    = delta_bf + 12582912;                // [3][4096][64]
    bf* cw_bf     = dbc_bf + 786432;                    // [3][512][512]
    bf* inw_bf    = cw_bf + 786432;                     // [3][2048][512]
    bf* xpw_bf    = inw_bf + 3145728;                   // [3][64][1024]
    bf* dtw_bf    = xpw_bf + 196608;                    // [3][1024][32]
    bf* outw_bf   = dtw_bf + 98304;                     // [3][512][1024]
    float* cwT    = (float*)(outw_bf + 1572864);        // [3][4][1024] f32
    float* A2T    = cwT + 12288;                        // [3][16][1024] f32
    float* Fbuf   = A2T + 49152;                        // [6][64][16][1024] f32
    float* sumd   = Fbuf + 6291456;                     // [6][64][1024] f32

    dim3 blk(256);

    // 0. fused prep
    prep_kernel<<<(1572864 + 1449984 + 12288 + 49152 + 255) / 256, blk, 0, stream>>>(
        a, t, v, sec_bf, couple_w, cw_bf, in_w, inw_bf, xproj_w, xpw_bf,
        dt_w, dtw_bf, out_w, outw_bf, conv_w, cwT, A_log, A2T);

    // 1. coupling (pipelined 128x128, 384 blocks co-resident)
    gemm_p128<8><<<dim3(32, 4, 3), 1024, 0, stream>>>(
        sec_bf, cw_bf, 512, 512, 2097152L, 262144L,
        nullptr, x_in_bf, 512, 2097152L,
        v, a, t, nullptr, 0L, coef);
    // 2. layernorm (bf16 in) -> bf16
    ln_kernel<<<3*4096, blk, 0, stream>>>(x_in_bf, xn_bf, norm_w, norm_b);
    // 3. in_proj -> xz  — pipelined 256x128, 768 blocks
    gemm8p_inproj<<<dim3(16, 16, 3), 1024, 0, stream>>>(xn_bf, inw_bf, xz_bf);
    // 4. conv + SiLU
    conv_silu_kernel<<<768, blk, 0, stream>>>(xz_bf, cwT, conv_b, xc_bf);
    // 5. x_proj -> dbc bf16 (BK=64, N=64 path)
    gemm_bf16<2, 64><<<dim3(32, 1, 3), blk, 0, stream>>>(
        xc_bf, xpw_bf, 1024, 1024, 1024, 4194304L, 65536L,
        nullptr, dbc_bf, 64, 262144L, nullptr, 0L, nullptr, nullptr, nullptr, 0L,
        nullptr, 0, nullptr, 0L, 0);
    // 6. delta = softplus(dt @ dt_w^T + dt_b) -> bf16
    gemm_bf16<4, 32><<<dim3(32, 8, 3), blk, 0, stream>>>(
        dbc_bf, dtw_bf, 32, 64, 32, 262144L, 32768L,
        nullptr, delta_bf, 1024, 4194304L, nullptr, 0L, nullptr, nullptr, nullptr, 0L,
        nullptr, 0, dt_b, 1024L, 1);
    // 7. chunk-parallel scan (2 channels/thread, 64 chunks of 32)
    scan_pass1_kernel<<<6*2*NCHUNK, blk, 0, stream>>>(delta_bf, xc_bf, dbc_bf, A2T, Fbuf, sumd);
    scan_pass2_kernel<<<(6*1024*16)/256, blk, 0, stream>>>(Fbuf, sumd, A2T);
    scan_pass3_kernel<<<6*2*NCHUNK, blk, 0, stream>>>(delta_bf, xc_bf, dbc_bf, xz_bf,
                                                      A2T, D_skip, Fbuf);
    // 8. out_proj + bf16 residual -> d_out (pipelined 128x128, K=1024)
    gemm_p128<16><<<dim3(32, 4, 3), 1024, 0, stream>>>(
        xz_bf, outw_bf, 2048, 1024, 8388608L, 524288L,
        out, nullptr, 512, 2097152L,
        nullptr, nullptr, nullptr, x_in_bf, 2097152L, nullptr);
}